// Round 1
// baseline (183.109 us; speedup 1.0000x reference)
//
#include <hip/hip_runtime.h>

#define S_LEN 2048
#define DIM   64
#define NBH   32            // B*H = 2*16
#define QBLK  64
#define KVBLK 64
#define NQT   (S_LEN/QBLK)  // 32
#define NPAIR (NQT/2)       // 16
#define NBLK  (NBH*NPAIR)   // 512

typedef __attribute__((ext_vector_type(4))) float f32x4;
typedef __attribute__((ext_vector_type(8))) short s16x8;
typedef __attribute__((ext_vector_type(4))) short s16x4;

#define MFMA_B16(A,B,C) __builtin_amdgcn_mfma_f32_16x16x32_bf16(A,B,C,0,0,0)

__device__ __forceinline__ short f2bf(float x){
  union{float f;unsigned u;} v; v.f=x;
  unsigned r = v.u + 0x7FFFu + ((v.u>>16)&1u);   // RNE
  return (short)(r>>16);
}
__device__ __forceinline__ float bf2f(short s){
  union{float f;unsigned u;} v; v.u=((unsigned)(unsigned short)s)<<16;
  return v.f;
}
// LDS swizzle (element-granularity XOR, 8-element groups => b128-safe).
// Chosen so reads (row = lane&15) AND staging writes (row strided by 4) spread.
__device__ __forceinline__ int swz(int row){
  return (((row&7) ^ ((row>>2)&7)) << 3);
}

__global__ __launch_bounds__(256) void fattn_fwd(
    const float* __restrict__ Qg, const float* __restrict__ Kg,
    const float* __restrict__ Vg, float* __restrict__ Og)
{
  // 32 KB LDS total -> LDS not the occupancy limiter (grid gives 2 blocks/CU)
  __shared__ __attribute__((aligned(16))) short Khi[KVBLK*DIM];
  __shared__ __attribute__((aligned(16))) short Klo[KVBLK*DIM];
  __shared__ __attribute__((aligned(16))) short Vt [DIM*KVBLK];   // V^T [dv][kv]
  __shared__ __attribute__((aligned(16))) short Pl [4*16*KVBLK];  // per-wave P

  // XCD-chunked bijective swizzle (512 % 8 == 0)
  int bid0 = blockIdx.x;
  int bid  = (bid0 & 7) * (NBLK/8) + (bid0 >> 3);
  int bh   = bid / NPAIR;
  int pr   = bid % NPAIR;

  const int tid = threadIdx.x;
  const int w   = tid >> 6;     // wave 0..3
  const int l   = tid & 63;
  const int l15 = l & 15;
  const int lg  = l >> 4;       // lane group 0..3

  const float* Qb = Qg + (size_t)bh * S_LEN * DIM;
  const float* Kb = Kg + (size_t)bh * S_LEN * DIM;
  const float* Vb = Vg + (size_t)bh * S_LEN * DIM;
  float*       Ob = Og + (size_t)bh * S_LEN * DIM;

  const float SC = 0.125f * 1.44269504088896f;  // (1/sqrt(64)) * log2(e)

  for (int half = 0; half < 2; ++half) {
    const int qt = half ? (NQT - 1 - pr) : pr;   // paired q-tiles: uniform work
    const int q0 = qt * QBLK;
    const int qg = q0 + w * 16 + l15;            // this lane's q (output column)

    // ---- hoist Q fragments (hi/lo split), B-operand layout:
    // lane: col=q (l&15), k = (lg*8 + s*32) + j, j=0..7 contiguous
    s16x8 qh[2], ql[2];
#pragma unroll
    for (int s = 0; s < 2; ++s) {
      const int dk0 = (lg << 3) + s * 32;
      const float* qp = Qb + (size_t)qg * DIM + dk0;
      float qv[8];
      *(f32x4*)&qv[0] = *(const f32x4*)qp;
      *(f32x4*)&qv[4] = *(const f32x4*)(qp + 4);
#pragma unroll
      for (int j = 0; j < 8; ++j) {
        short h = f2bf(qv[j]);
        qh[s][j] = h;
        ql[s][j] = f2bf(qv[j] - bf2f(h));
      }
    }

    f32x4 o[4];
#pragma unroll
    for (int d = 0; d < 4; ++d) o[d] = f32x4{0.f,0.f,0.f,0.f};
    float m = -INFINITY, lsum = 0.f;

    const int ntiles = qt + 1;
    for (int t = 0; t < ntiles; ++t) {
      const int kv0 = t * KVBLK;
      __syncthreads();   // previous tile's readers done before re-staging
      // ---- stage K (hi/lo) and V^T, fp32 -> bf16, swizzled
      {
        const int row = tid >> 4;          // 0..15
        const int c4  = (tid & 15) << 2;   // 0,4,..,60
#pragma unroll
        for (int i = 0; i < 4; ++i) {
          const int r = row + (i << 4);    // kv row 0..63
          const f32x4 kv4 = *(const f32x4*)(Kb + (size_t)(kv0 + r) * DIM + c4);
          const f32x4 vv4 = *(const f32x4*)(Vb + (size_t)(kv0 + r) * DIM + c4);
          const int cs = c4 ^ swz(r);
          s16x4 kh, kl;
#pragma unroll
          for (int j = 0; j < 4; ++j) {
            short h = f2bf(kv4[j]);
            kh[j] = h;
            kl[j] = f2bf(kv4[j] - bf2f(h));
          }
          *(s16x4*)&Khi[r * DIM + cs] = kh;
          *(s16x4*)&Klo[r * DIM + cs] = kl;
#pragma unroll
          for (int j = 0; j < 4; ++j) {    // transpose V into Vt[dv][kv]
            const int dv = c4 + j;
            Vt[dv * KVBLK + (r ^ swz(dv))] = f2bf(vv4[j]);
          }
        }
      }
      __syncthreads();

      // ---- QK^T (swapped: S^T = K · Q^T), fp32-accurate via hi/lo split
      f32x4 acc[4];
#pragma unroll
      for (int f = 0; f < 4; ++f) acc[f] = f32x4{0.f,0.f,0.f,0.f};
#pragma unroll
      for (int f = 0; f < 4; ++f) {
        const int kr = f * 16 + l15;       // A row = kv
#pragma unroll
        for (int s = 0; s < 2; ++s) {
          const int dk = (((lg << 3) + s * 32) ^ swz(kr));
          s16x8 ah = *(const s16x8*)&Khi[kr * DIM + dk];
          s16x8 al = *(const s16x8*)&Klo[kr * DIM + dk];
          acc[f] = MFMA_B16(ah, qh[s], acc[f]);
          acc[f] = MFMA_B16(ah, ql[s], acc[f]);
          acc[f] = MFMA_B16(al, qh[s], acc[f]);
        }
      }

      // ---- scale + causal mask (only diagonal tile), log2-domain logits
      const bool diag = (t == qt);
      float z[4][4];
#pragma unroll
      for (int f = 0; f < 4; ++f)
#pragma unroll
        for (int r = 0; r < 4; ++r) {
          float zz = acc[f][r] * SC;
          if (diag) {
            const int kvg = kv0 + f * 16 + (lg << 2) + r;
            if (kvg > qg) zz = -INFINITY;
          }
          z[f][r] = zz;
        }

      // ---- online softmax (lane owns one q; reduce over kv: regs + 2 shfl)
      float pm = z[0][0];
#pragma unroll
      for (int f = 0; f < 4; ++f)
#pragma unroll
        for (int r = 0; r < 4; ++r) pm = fmaxf(pm, z[f][r]);
      pm = fmaxf(pm, __shfl_xor(pm, 16));
      pm = fmaxf(pm, __shfl_xor(pm, 32));
      const float mn = fmaxf(m, pm);
      const float alpha = exp2f(m - mn);
      float p[4][4];
      float rs = 0.f;
#pragma unroll
      for (int f = 0; f < 4; ++f)
#pragma unroll
        for (int r = 0; r < 4; ++r) {
          const float pv = exp2f(z[f][r] - mn);
          p[f][r] = pv;
          rs += pv;
        }
      rs += __shfl_xor(rs, 16);
      rs += __shfl_xor(rs, 32);
      lsum = lsum * alpha + rs;
      m = mn;
#pragma unroll
      for (int d = 0; d < 4; ++d) o[d] *= alpha;

      // ---- P -> LDS (wave-private, C-frag layout in, B-frag layout out)
      short* Pw = &Pl[w * 16 * KVBLK];
#pragma unroll
      for (int f = 0; f < 4; ++f) {
        s16x4 pk;
#pragma unroll
        for (int r = 0; r < 4; ++r) pk[r] = f2bf(p[f][r]);
        const int kvc = (f * 16 + (lg << 2)) ^ swz(l15);
        *(s16x4*)&Pw[l15 * KVBLK + kvc] = pk;
      }
      // (same-wave LDS write->read: compiler inserts lgkmcnt wait, no barrier)

      // ---- PV: O^T += V^T · P^T
#pragma unroll
      for (int s = 0; s < 2; ++s) {
        const int kv8 = (lg << 3) + s * 32;
        s16x8 pf = *(const s16x8*)&Pw[l15 * KVBLK + (kv8 ^ swz(l15))];
#pragma unroll
        for (int d = 0; d < 4; ++d) {
          const int dv = d * 16 + l15;
          s16x8 vf = *(const s16x8*)&Vt[dv * KVBLK + (kv8 ^ swz(dv))];
          o[d] = MFMA_B16(vf, pf, o[d]);
        }
      }
    }

    // ---- epilogue: normalize and store (fp32, dwordx4, rows = dv frags)
    const float inv = 1.0f / lsum;
#pragma unroll
    for (int d = 0; d < 4; ++d) {
      f32x4 ov;
#pragma unroll
      for (int r = 0; r < 4; ++r) ov[r] = o[d][r] * inv;
      *(f32x4*)(Ob + (size_t)qg * DIM + d * 16 + (lg << 2)) = ov;
    }
  }
}

extern "C" void kernel_launch(void* const* d_in, const int* in_sizes, int n_in,
                              void* d_out, int out_size, void* d_ws, size_t ws_size,
                              hipStream_t stream) {
  const float* Q = (const float*)d_in[0];
  const float* K = (const float*)d_in[1];
  const float* V = (const float*)d_in[2];
  // d_in[3] = causal mask: known statically, unused
  float* O = (float*)d_out;
  fattn_fwd<<<dim3(NBLK), dim3(256), 0, stream>>>(Q, K, V, O);
}